// Round 2
// baseline (629.027 us; speedup 1.0000x reference)
//
#include <hip/hip_runtime.h>
#include <math.h>

namespace {
constexpr int kNRays = 131072;
constexpr int kLanesPerRay = 4;   // each lane composites 8 layers (2 rgb groups)
constexpr int kGroupsPerLane = 2;
constexpr int kSub = 4;
constexpr int kH = 960;
constexpr int kW = 1920;
constexpr int kHW = kH * kW;

__device__ __forceinline__ float sigmoidf(float z) {
    return 1.0f / (1.0f + __expf(-z));
}

// torch grid_sample: bilinear, align_corners=True, zeros padding.
__device__ __forceinline__ void bilin_setup(float gx, float gy, int idx[4], float w[4]) {
    float x = (gx + 1.0f) * (0.5f * (float)(kW - 1));
    float y = (gy + 1.0f) * (0.5f * (float)(kH - 1));
    float x0f = floorf(x), y0f = floorf(y);
    float wx1 = x - x0f, wy1 = y - y0f;
    float wx0 = 1.0f - wx1, wy0 = 1.0f - wy1;
    bool vx0 = (x0f >= 0.0f) && (x0f <= (float)(kW - 1));
    bool vx1 = (x0f + 1.0f >= 0.0f) && (x0f + 1.0f <= (float)(kW - 1));
    bool vy0 = (y0f >= 0.0f) && (y0f <= (float)(kH - 1));
    bool vy1 = (y0f + 1.0f >= 0.0f) && (y0f + 1.0f <= (float)(kH - 1));
    int x0 = min(max((int)x0f, 0), kW - 1);
    int x1 = min(max((int)x0f + 1, 0), kW - 1);
    int y0 = min(max((int)y0f, 0), kH - 1);
    int y1 = min(max((int)y0f + 1, 0), kH - 1);
    idx[0] = y0 * kW + x0; w[0] = (vy0 && vx0) ? wy0 * wx0 : 0.0f;
    idx[1] = y0 * kW + x1; w[1] = (vy0 && vx1) ? wy0 * wx1 : 0.0f;
    idx[2] = y1 * kW + x0; w[2] = (vy1 && vx0) ? wy1 * wx0 : 0.0f;
    idx[3] = y1 * kW + x1; w[3] = (vy1 && vx1) ? wy1 * wx1 : 0.0f;
}
} // namespace

__global__ __launch_bounds__(256, 8) void msi_field_kernel(
    const float* __restrict__ origins,
    const float* __restrict__ dirs,
    const float* __restrict__ pose,
    const float* __restrict__ alpha,
    const float* __restrict__ rgb,
    const float* __restrict__ planes,
    float* __restrict__ out)
{
    int tid = blockIdx.x * blockDim.x + threadIdx.x;
    int i = tid / kLanesPerRay;          // ray index
    int r = tid & (kLanesPerRay - 1);    // lane-in-ray: owns layers [r*8, r*8+8)
    if (i >= kNRays) return;

    float cx = pose[3], cy = pose[7], cz = pose[11];
    float ox = origins[3*i+0], oy = origins[3*i+1], oz = origins[3*i+2];
    float dx = dirs[3*i+0],    dy = dirs[3*i+1],    dz = dirs[3*i+2];

    float rx = ox - cx, ry = oy - cy, rz = oz - cz;
    float a  = dx*dx + dy*dy + dz*dz;
    float b  = 2.0f * (dx*rx + dy*ry + dz*rz);
    float rr = rx*rx + ry*ry + rz*rz;
    float inv2a = 1.0f / (2.0f * a);

    // local (per-lane) composite over this lane's 8 layers
    float T = 1.0f;
    float accR = 0.0f, accG = 0.0f, accB = 0.0f;
    float sr = 0.0f, sg = 0.0f, sb = 0.0f;

    #pragma unroll
    for (int g = 0; g < kGroupsPerLane; ++g) {
        const int nl = r * kGroupsPerLane + g;   // rgb group index
        #pragma unroll
        for (int s = 0; s < kSub; ++s) {
            const int l = nl * kSub + s;
            float p = planes[l];
            float c = rr - p * p;
            float disc = b * b - 4.0f * a * c;
            float sq = sqrtf(disc);
            float t0 = (-b + sq) * inv2a;
            float t1 = (-b - sq) * inv2a;
            bool mask = (t0 * t1) < 0.0f;

            float hx = rx + dx * t0;
            float hy = ry + dy * t0;
            float hz = rz + dz * t0;
            float invp = 1.0f / p;
            float xn = hx * invp, yn = hy * invp, zn = hz * invp;

            float gx = zn;
            float gy = atan2f(yn, -xn) * 0.31830988618379067f;

            int idx[4]; float w[4];
            bilin_setup(gx, gy, idx, w);

            const float* aimg = alpha + (size_t)l * kHW;
            float av = w[0]*aimg[idx[0]] + w[1]*aimg[idx[1]]
                     + w[2]*aimg[idx[2]] + w[3]*aimg[idx[3]];
            float asig = mask ? sigmoidf(av + 1.0f) : 0.0f;

            if (s == 0) {
                const float* rimg = rgb + (size_t)nl * 3 * kHW;
                const float* gimg = rimg + kHW;
                const float* bimg = rimg + 2 * kHW;
                float rv = w[0]*rimg[idx[0]] + w[1]*rimg[idx[1]]
                         + w[2]*rimg[idx[2]] + w[3]*rimg[idx[3]];
                float gv = w[0]*gimg[idx[0]] + w[1]*gimg[idx[1]]
                         + w[2]*gimg[idx[2]] + w[3]*gimg[idx[3]];
                float bv = w[0]*bimg[idx[0]] + w[1]*bimg[idx[1]]
                         + w[2]*bimg[idx[2]] + w[3]*bimg[idx[3]];
                sr = sigmoidf(rv); sg = sigmoidf(gv); sb = sigmoidf(bv);
            }

            float wt = T * asig;
            accR += wt * sr;
            accG += wt * sg;
            accB += wt * sb;
            T *= (1.0f - asig);
        }
    }

    // Ordered segmented combine across the 4 lanes of this ray.
    // op: (Ta,Sa) ∘ (Tb,Sb) = (Ta*Tb, Sa + Ta*Sb); lane r holds segment r.
    #pragma unroll
    for (int m = 1; m <= 2; m <<= 1) {
        float pT = __shfl_xor(T,    m);
        float pR = __shfl_xor(accR, m);
        float pG = __shfl_xor(accG, m);
        float pB = __shfl_xor(accB, m);
        if ((r & m) == 0) {
            // partner segment comes after mine
            accR += T * pR; accG += T * pG; accB += T * pB;
            T *= pT;
        } else {
            // partner segment comes before mine
            accR = pR + pT * accR; accG = pG + pT * accG; accB = pB + pT * accB;
            T = pT * T;
        }
    }

    if (r == 0) {
        out[i]            = accR;
        out[kNRays + i]   = accG;
        out[2*kNRays + i] = accB;
    }
}

extern "C" void kernel_launch(void* const* d_in, const int* in_sizes, int n_in,
                              void* d_out, int out_size, void* d_ws, size_t ws_size,
                              hipStream_t stream) {
    const float* origins = (const float*)d_in[0];
    const float* dirs    = (const float*)d_in[1];
    const float* pose    = (const float*)d_in[2];
    const float* alpha   = (const float*)d_in[3];
    const float* rgb     = (const float*)d_in[4];
    const float* planes  = (const float*)d_in[5];
    float* out = (float*)d_out;

    const int total = kNRays * kLanesPerRay;
    dim3 block(256);
    dim3 grid((total + 255) / 256);
    hipLaunchKernelGGL(msi_field_kernel, grid, block, 0, stream,
                       origins, dirs, pose, alpha, rgb, planes, out);
}

// Round 6
// 495.453 us; speedup vs baseline: 1.2696x; 1.2696x over previous
//
#include <hip/hip_runtime.h>
#include <math.h>

namespace {
constexpr int kNRays = 131072;
constexpr int kNL = 8;
constexpr int kSub = 4;
constexpr int kH = 960;
constexpr int kW = 1920;
constexpr int kHW = kH * kW;
constexpr int kGridB = 64;                    // sort buckets per axis
constexpr int kNBuckets = kGridB * kGridB;    // 4096
constexpr int kKeyPlane = 20;                 // representative sphere for sort key

__device__ __forceinline__ float sigmoidf(float z) {
    return 1.0f / (1.0f + __expf(-z));
}

__device__ __forceinline__ unsigned morton2(unsigned x, unsigned y) {
    unsigned r = 0;
    #pragma unroll
    for (int i = 0; i < 6; ++i) {
        r |= ((x >> i) & 1u) << (2 * i);
        r |= ((y >> i) & 1u) << (2 * i + 1);
    }
    return r;
}

// Shared ray->uv math (approximate sort key only; not correctness-critical).
__device__ __forceinline__ void ray_uv(float rx, float ry, float rz,
                                       float dx, float dy, float dz,
                                       float p, float& gx, float& gy) {
    float a  = dx*dx + dy*dy + dz*dz;
    float b  = 2.0f * (dx*rx + dy*ry + dz*rz);
    float rr = rx*rx + ry*ry + rz*rz;
    float c = rr - p * p;
    float disc = b * b - 4.0f * a * c;
    float sq = sqrtf(fmaxf(disc, 0.0f));
    float t0 = (-b + sq) / (2.0f * a);
    float hx = rx + dx * t0;
    float hy = ry + dy * t0;
    float hz = rz + dz * t0;
    float invp = 1.0f / p;
    float xn = hx * invp, yn = hy * invp, zn = hz * invp;
    gx = zn;
    gy = atan2f(yn, -xn) * 0.31830988618379067f;
}

// torch grid_sample: bilinear, align_corners=True, zeros padding.
__device__ __forceinline__ void bilin_setup(float gx, float gy, int idx[4], float w[4]) {
    float x = (gx + 1.0f) * (0.5f * (float)(kW - 1));
    float y = (gy + 1.0f) * (0.5f * (float)(kH - 1));
    float x0f = floorf(x), y0f = floorf(y);
    float wx1 = x - x0f, wy1 = y - y0f;
    float wx0 = 1.0f - wx1, wy0 = 1.0f - wy1;
    bool vx0 = (x0f >= 0.0f) && (x0f <= (float)(kW - 1));
    bool vx1 = (x0f + 1.0f >= 0.0f) && (x0f + 1.0f <= (float)(kW - 1));
    bool vy0 = (y0f >= 0.0f) && (y0f <= (float)(kH - 1));
    bool vy1 = (y0f + 1.0f >= 0.0f) && (y0f + 1.0f <= (float)(kH - 1));
    int x0 = min(max((int)x0f, 0), kW - 1);
    int x1 = min(max((int)x0f + 1, 0), kW - 1);
    int y0 = min(max((int)y0f, 0), kH - 1);
    int y1 = min(max((int)y0f + 1, 0), kH - 1);
    idx[0] = y0 * kW + x0; w[0] = (vy0 && vx0) ? wy0 * wx0 : 0.0f;
    idx[1] = y0 * kW + x1; w[1] = (vy0 && vx1) ? wy0 * wx1 : 0.0f;
    idx[2] = y1 * kW + x0; w[2] = (vy1 && vx0) ? wy1 * wx0 : 0.0f;
    idx[3] = y1 * kW + x1; w[3] = (vy1 && vx1) ? wy1 * wx1 : 0.0f;
}
} // namespace

// ---- Pass 1: sort key + histogram -----------------------------------------
__global__ __launch_bounds__(256) void key_hist_kernel(
    const float* __restrict__ origins, const float* __restrict__ dirs,
    const float* __restrict__ pose, const float* __restrict__ planes,
    unsigned* __restrict__ keys, unsigned* __restrict__ hist)
{
    int i = blockIdx.x * blockDim.x + threadIdx.x;
    if (i >= kNRays) return;
    float cx = pose[3], cy = pose[7], cz = pose[11];
    float rx = origins[3*i+0] - cx, ry = origins[3*i+1] - cy, rz = origins[3*i+2] - cz;
    float dx = dirs[3*i+0], dy = dirs[3*i+1], dz = dirs[3*i+2];
    float gx, gy;
    ray_uv(rx, ry, rz, dx, dy, dz, planes[kKeyPlane], gx, gy);
    int qu = min(max((int)((gx * 0.5f + 0.5f) * (float)kGridB), 0), kGridB - 1);
    int qv = min(max((int)((gy * 0.5f + 0.5f) * (float)kGridB), 0), kGridB - 1);
    unsigned k = morton2((unsigned)qu, (unsigned)qv);
    keys[i] = k;
    atomicAdd(&hist[k], 1u);
}

// ---- Pass 2: exclusive scan over 4096 bins (one block) ---------------------
__global__ __launch_bounds__(256) void scan_kernel(unsigned* __restrict__ hist)
{
    __shared__ unsigned part[256];
    int t = threadIdx.x;
    unsigned loc[kNBuckets / 256];
    unsigned sum = 0;
    #pragma unroll
    for (int j = 0; j < kNBuckets / 256; ++j) {
        loc[j] = hist[t * (kNBuckets / 256) + j];
        sum += loc[j];
    }
    part[t] = sum;
    __syncthreads();
    for (int off = 1; off < 256; off <<= 1) {
        unsigned v = (t >= off) ? part[t - off] : 0u;
        __syncthreads();
        part[t] += v;
        __syncthreads();
    }
    unsigned prefix = part[t] - sum;   // exclusive
    #pragma unroll
    for (int j = 0; j < kNBuckets / 256; ++j) {
        unsigned v = loc[j];
        hist[t * (kNBuckets / 256) + j] = prefix;
        prefix += v;
    }
}

// ---- Pass 3: scatter ray ids into sorted order -----------------------------
__global__ __launch_bounds__(256) void scatter_kernel(
    const unsigned* __restrict__ keys, unsigned* __restrict__ offs,
    unsigned* __restrict__ perm)
{
    int i = blockIdx.x * blockDim.x + threadIdx.x;
    if (i >= kNRays) return;
    unsigned pos = atomicAdd(&offs[keys[i]], 1u);
    perm[pos] = (unsigned)i;
}

// ---- Pass 4: main render, rays in sorted order -----------------------------
__global__ __launch_bounds__(256) void msi_field_kernel(
    const float* __restrict__ origins,
    const float* __restrict__ dirs,
    const float* __restrict__ pose,
    const float* __restrict__ alpha,
    const float* __restrict__ rgb,
    const float* __restrict__ planes,
    const unsigned* __restrict__ perm,
    float* __restrict__ out)
{
    int slot = blockIdx.x * blockDim.x + threadIdx.x;
    if (slot >= kNRays) return;
    int i = (int)perm[slot];

    float cx = pose[3], cy = pose[7], cz = pose[11];
    float ox = origins[3*i+0], oy = origins[3*i+1], oz = origins[3*i+2];
    float dx = dirs[3*i+0],    dy = dirs[3*i+1],    dz = dirs[3*i+2];

    float rx = ox - cx, ry = oy - cy, rz = oz - cz;
    float a  = dx*dx + dy*dy + dz*dz;
    float b  = 2.0f * (dx*rx + dy*ry + dz*rz);
    float rr = rx*rx + ry*ry + rz*rz;
    float inv2a = 1.0f / (2.0f * a);

    float T = 1.0f;
    float accR = 0.0f, accG = 0.0f, accB = 0.0f;
    float sr = 0.0f, sg = 0.0f, sb = 0.0f;

    for (int nl = 0; nl < kNL; ++nl) {
        #pragma unroll
        for (int s = 0; s < kSub; ++s) {
            const int l = nl * kSub + s;
            float p = planes[l];
            float c = rr - p * p;
            float disc = b * b - 4.0f * a * c;
            float sq = sqrtf(disc);
            float t0 = (-b + sq) * inv2a;
            float t1 = (-b - sq) * inv2a;
            bool mask = (t0 * t1) < 0.0f;

            float hx = rx + dx * t0;
            float hy = ry + dy * t0;
            float hz = rz + dz * t0;
            float invp = 1.0f / p;
            float xn = hx * invp, yn = hy * invp, zn = hz * invp;

            float gx = zn;
            float gy = atan2f(yn, -xn) * 0.31830988618379067f;

            int idx[4]; float w[4];
            bilin_setup(gx, gy, idx, w);

            const float* aimg = alpha + (size_t)l * kHW;
            float av = w[0]*aimg[idx[0]] + w[1]*aimg[idx[1]]
                     + w[2]*aimg[idx[2]] + w[3]*aimg[idx[3]];
            float asig = mask ? sigmoidf(av + 1.0f) : 0.0f;

            if (s == 0) {
                const float* rimg = rgb + (size_t)nl * 3 * kHW;
                const float* gimg = rimg + kHW;
                const float* bimg = rimg + 2 * kHW;
                float rv = w[0]*rimg[idx[0]] + w[1]*rimg[idx[1]]
                         + w[2]*rimg[idx[2]] + w[3]*rimg[idx[3]];
                float gv = w[0]*gimg[idx[0]] + w[1]*gimg[idx[1]]
                         + w[2]*gimg[idx[2]] + w[3]*gimg[idx[3]];
                float bv = w[0]*bimg[idx[0]] + w[1]*bimg[idx[1]]
                         + w[2]*bimg[idx[2]] + w[3]*bimg[idx[3]];
                sr = sigmoidf(rv); sg = sigmoidf(gv); sb = sigmoidf(bv);
            }

            float wt = T * asig;
            accR += wt * sr;
            accG += wt * sg;
            accB += wt * sb;
            T *= (1.0f - asig);
        }
    }

    out[i]            = accR;
    out[kNRays + i]   = accG;
    out[2*kNRays + i] = accB;
}

extern "C" void kernel_launch(void* const* d_in, const int* in_sizes, int n_in,
                              void* d_out, int out_size, void* d_ws, size_t ws_size,
                              hipStream_t stream) {
    const float* origins = (const float*)d_in[0];
    const float* dirs    = (const float*)d_in[1];
    const float* pose    = (const float*)d_in[2];
    const float* alpha   = (const float*)d_in[3];
    const float* rgb     = (const float*)d_in[4];
    const float* planes  = (const float*)d_in[5];
    float* out = (float*)d_out;

    // Workspace layout: [hist/offs: 4096 u32][keys: kNRays u32][perm: kNRays u32]
    unsigned* hist = (unsigned*)d_ws;
    unsigned* keys = hist + kNBuckets;
    unsigned* perm = keys + kNRays;

    hipMemsetAsync(hist, 0, kNBuckets * sizeof(unsigned), stream);

    dim3 block(256);
    dim3 gridR((kNRays + 255) / 256);
    hipLaunchKernelGGL(key_hist_kernel, gridR, block, 0, stream,
                       origins, dirs, pose, planes, keys, hist);
    hipLaunchKernelGGL(scan_kernel, dim3(1), block, 0, stream, hist);
    hipLaunchKernelGGL(scatter_kernel, gridR, block, 0, stream, keys, hist, perm);
    hipLaunchKernelGGL(msi_field_kernel, gridR, block, 0, stream,
                       origins, dirs, pose, alpha, rgb, planes, perm, out);
}